// Round 9
// baseline (145.352 us; speedup 1.0000x reference)
//
#include <hip/hip_runtime.h>
#include <stdint.h>
#include <stddef.h>

// Causal attention fused layer for MI355X (gfx950).
// B=2 T=2048 C=1024 H=16 D=64.
// Pipeline: cvt x -> bf16 | transpose-cvt weights -> bf16 N*K | QKV GEMM (mfma 16x16x32 bf16)
//           | V transpose (B,H,D,T) | flash attention (swapped QK^T, 4-wave blocks sharing
//             dbuf LDS 128-kv tiles, counted-vmcnt pipeline, XOR-swizzled ds_read,
//             in-register softmax with tree reductions) | out GEMM f32.
// Workspace layout (needs >= 48 MB):
//   [0,8MB)   x bf16            (M=4096 x K=1024)
//   [8,16MB)  Wt q,k,v,o bf16   (4 x 1024x1024, transposed N x K)
//   [16,32MB) Q,K bf16          ((B,H,T,D)), Q pre-scaled by 0.125*log2(e)
//   [32,40MB) V^T bf16          ((B,H,D,T))
//   [40,48MB) Vtmp then O bf16  (V normal layout, overwritten by attn output (B,T,C))

#define B_SZ 2
#define T_SZ 2048
#define C_SZ 1024
#define H_SZ 16
#define D_SZ 64
#define M_SZ (B_SZ * T_SZ)              // 4096
#define BHTD (B_SZ * H_SZ * T_SZ * D_SZ) // 4194304
#define CC (C_SZ * C_SZ)                 // 1048576

typedef __attribute__((ext_vector_type(8))) __bf16 bf16x8;
typedef __attribute__((ext_vector_type(4))) float f32x4;
typedef __attribute__((ext_vector_type(16))) float f32x16;

__device__ __forceinline__ unsigned short f2bf(float f) {
    union { float f; unsigned u; } v; v.f = f;
    v.u += 0x7fffu + ((v.u >> 16) & 1u);   // round-to-nearest-even
    return (unsigned short)(v.u >> 16);
}

__device__ __forceinline__ unsigned pkbf(float lo, float hi_) {
    union { unsigned u; __bf16 h[2]; } r;
    r.h[0] = (__bf16)lo; r.h[1] = (__bf16)hi_;    // compiler emits v_cvt_pk_bf16_f32
    return r.u;
}

__device__ __forceinline__ void load_lds16(const unsigned short* g, unsigned short* l) {
    __builtin_amdgcn_global_load_lds(
        (const __attribute__((address_space(1))) void*)g,
        (__attribute__((address_space(3))) void*)l, 16, 0, 0);
}

// ---------------- conversion kernels ----------------

__global__ void cvt_x_kernel(const float4* __restrict__ in, ushort4* __restrict__ out, int n4) {
    int stride = gridDim.x * blockDim.x;
    for (int i = blockIdx.x * blockDim.x + threadIdx.x; i < n4; i += stride) {
        float4 v = in[i];
        ushort4 o;
        o.x = f2bf(v.x); o.y = f2bf(v.y); o.z = f2bf(v.z); o.w = f2bf(v.w);
        out[i] = o;
    }
}

__global__ __launch_bounds__(256) void transpose_cvt_kernel(
    const float* __restrict__ W0, const float* __restrict__ W1,
    const float* __restrict__ W2, const float* __restrict__ W3,
    unsigned short* __restrict__ T0, unsigned short* __restrict__ T1,
    unsigned short* __restrict__ T2, unsigned short* __restrict__ T3)
{
    __shared__ float tile[32][33];
    const float* W; unsigned short* Wt;
    switch (blockIdx.z) {
        case 0: W = W0; Wt = T0; break;
        case 1: W = W1; Wt = T1; break;
        case 2: W = W2; Wt = T2; break;
        default: W = W3; Wt = T3; break;
    }
    const int tx = threadIdx.x, ty = threadIdx.y;     // 32 x 8
    const int n0 = blockIdx.x * 32, k0 = blockIdx.y * 32;
    #pragma unroll
    for (int i = 0; i < 4; i++)
        tile[ty + i * 8][tx] = W[(size_t)(k0 + ty + i * 8) * C_SZ + n0 + tx];
    __syncthreads();
    #pragma unroll
    for (int i = 0; i < 4; i++)
        Wt[(size_t)(n0 + ty + i * 8) * C_SZ + k0 + tx] = f2bf(tile[tx][ty + i * 8]);
}

// V (B,H,T,D) -> V^T (B,H,D,T), per-head 2048x64 transpose in 32x32 tiles.
__global__ __launch_bounds__(256) void vt_kernel(
    const unsigned short* __restrict__ V, unsigned short* __restrict__ Vt)
{
    __shared__ unsigned short tile[32][33];
    const int bh = blockIdx.z;
    const int t0 = blockIdx.x * 32, d0 = blockIdx.y * 32;
    const unsigned short* src = V + (size_t)bh * T_SZ * D_SZ;
    unsigned short* dst = Vt + (size_t)bh * T_SZ * D_SZ;
    const int tx = threadIdx.x, ty = threadIdx.y;     // 32 x 8
    #pragma unroll
    for (int i = 0; i < 4; i++)
        tile[ty + i * 8][tx] = src[(size_t)(t0 + ty + i * 8) * D_SZ + d0 + tx];
    __syncthreads();
    #pragma unroll
    for (int i = 0; i < 4; i++)
        dst[(size_t)(d0 + ty + i * 8) * T_SZ + t0 + tx] = tile[tx][ty + i * 8];
}

// ---------------- GEMM core (m97 structure: 128x128 tile, BK=32) ----------------

__device__ __forceinline__ void gemm_tile_core(
    const unsigned short* __restrict__ A,
    const unsigned short* __restrict__ Bt,
    unsigned short* As, unsigned short* Bs,
    int m0, int n0, f32x4 acc[4][4])
{
    const int tid = threadIdx.x;
    const int lane = tid & 63;
    const int w = tid >> 6;
    const int l15 = lane & 15, lg = lane >> 4;
    const int wr = (w >> 1) * 64, wc = (w & 1) * 64;

    const unsigned short* Ag0 = A + (size_t)(m0 + (tid >> 2)) * C_SZ + (tid & 3) * 8;
    const unsigned short* Ag1 = Ag0 + (size_t)64 * C_SZ;
    const unsigned short* Bg0 = Bt + (size_t)(n0 + (tid >> 2)) * C_SZ + (tid & 3) * 8;
    const unsigned short* Bg1 = Bg0 + (size_t)64 * C_SZ;
    unsigned short* As0 = As + w * 512;
    unsigned short* As1 = As + 2048 + w * 512;
    unsigned short* Bs0 = Bs + w * 512;
    unsigned short* Bs1 = Bs + 2048 + w * 512;

    for (int k0 = 0; k0 < C_SZ; k0 += 32) {
        load_lds16(Ag0 + k0, As0);
        load_lds16(Ag1 + k0, As1);
        load_lds16(Bg0 + k0, Bs0);
        load_lds16(Bg1 + k0, Bs1);
        __syncthreads();
        bf16x8 af[4], bfv[4];
        const bf16x8* Ap = (const bf16x8*)As;
        const bf16x8* Bp = (const bf16x8*)Bs;
        #pragma unroll
        for (int m = 0; m < 4; m++) af[m] = Ap[(wr + m * 16 + l15) * 4 + lg];
        #pragma unroll
        for (int n = 0; n < 4; n++) bfv[n] = Bp[(wc + n * 16 + l15) * 4 + lg];
        #pragma unroll
        for (int m = 0; m < 4; m++)
            #pragma unroll
            for (int n = 0; n < 4; n++)
                acc[m][n] = __builtin_amdgcn_mfma_f32_16x16x32_bf16(af[m], bfv[n], acc[m][n], 0, 0, 0);
        __syncthreads();
    }
}

// QKV projection GEMM. gridDim.z in {0,1,2} selects Q/K/V.
// Q,K -> (B,H,T,D) bf16 (Q scaled by 0.125*log2(e)); V -> Vtmp (B,H,T,D).
__global__ __launch_bounds__(256) void gemm_qkv_kernel(
    const unsigned short* __restrict__ A,
    const unsigned short* __restrict__ WtBase,
    const float* __restrict__ bq, const float* __restrict__ bk, const float* __restrict__ bv,
    unsigned short* __restrict__ QKV, unsigned short* __restrict__ Vtmp)
{
    __shared__ unsigned short As[4096], Bs[4096];
    const int z = blockIdx.z;
    const unsigned short* Bt = WtBase + (size_t)z * CC;
    const float* bias = (z == 0) ? bq : (z == 1) ? bk : bv;
    const float scale = (z == 0) ? 0.18033688011112042f : 1.0f;  // 0.125 * log2(e)
    unsigned short* Out = (z == 2) ? Vtmp : QKV + (size_t)z * BHTD;

    f32x4 acc[4][4];
    f32x4 zero4 = {0.f, 0.f, 0.f, 0.f};
    #pragma unroll
    for (int m = 0; m < 4; m++)
        #pragma unroll
        for (int n = 0; n < 4; n++) acc[m][n] = zero4;

    const int m0 = blockIdx.y * 128, n0 = blockIdx.x * 128;
    gemm_tile_core(A, Bt, As, Bs, m0, n0, acc);

    const int lane = threadIdx.x & 63;
    const int w = threadIdx.x >> 6;
    const int l15 = lane & 15, lg = lane >> 4;
    const int wr = (w >> 1) * 64, wc = (w & 1) * 64;
    #pragma unroll
    for (int n = 0; n < 4; n++) {
        const int col = n0 + wc + n * 16 + l15;
        const float bias_v = bias[col];
        const int h = col >> 6, d = col & 63;
        #pragma unroll
        for (int m = 0; m < 4; m++) {
            #pragma unroll
            for (int j = 0; j < 4; j++) {
                const int row = m0 + wr + m * 16 + lg * 4 + j;   // global M row = b*T + t
                const int b = row >> 11, t = row & (T_SZ - 1);
                Out[(((size_t)(b * H_SZ + h)) * T_SZ + t) * D_SZ + d] =
                    f2bf((acc[m][n][j] + bias_v) * scale);
            }
        }
    }
}

// Output projection GEMM: O(bf16, M x C) @ Wo^T + bo -> f32 (B,T,C).
__global__ __launch_bounds__(256) void gemm_out_kernel(
    const unsigned short* __restrict__ A,
    const unsigned short* __restrict__ Bt,
    const float* __restrict__ bo,
    float* __restrict__ Out)
{
    __shared__ unsigned short As[4096], Bs[4096];
    f32x4 acc[4][4];
    f32x4 zero4 = {0.f, 0.f, 0.f, 0.f};
    #pragma unroll
    for (int m = 0; m < 4; m++)
        #pragma unroll
        for (int n = 0; n < 4; n++) acc[m][n] = zero4;

    const int m0 = blockIdx.y * 128, n0 = blockIdx.x * 128;
    gemm_tile_core(A, Bt, As, Bs, m0, n0, acc);

    const int lane = threadIdx.x & 63;
    const int w = threadIdx.x >> 6;
    const int l15 = lane & 15, lg = lane >> 4;
    const int wr = (w >> 1) * 64, wc = (w & 1) * 64;
    #pragma unroll
    for (int n = 0; n < 4; n++) {
        const int col = n0 + wc + n * 16 + l15;
        const float bias_v = bo[col];
        #pragma unroll
        for (int m = 0; m < 4; m++) {
            #pragma unroll
            for (int j = 0; j < 4; j++) {
                const int row = m0 + wr + m * 16 + lg * 4 + j;
                Out[(size_t)row * C_SZ + col] = acc[m][n][j] + bias_v;
            }
        }
    }
}

// ---------------- flash attention (swapped QK^T, KVBLK=128, counted-vmcnt dbuf) ----------------
// grid 512 x 256thr (4 waves). qt pairing decode (harmless heuristic), bh = idx&31.
// Block owns 128 q rows (wave w: qw = qt*128 + 32w); all waves share staged 128-kv tiles
// (K 16KB + V^T 16KB per buffer, double-buffered = 64KB LDS -> 2 blocks/CU).
// With KVBLK=128, ALL waves have tlast == ntb-1: no idle waves, uniform loop.
// Pipeline (T3+T4): issue 8 STAGE loads for t+1 -> s_waitcnt vmcnt(8) (tile t landed, t+1 in
// flight) -> s_barrier -> compute(t) -> s_barrier. vmcnt never 0 in-loop (last iter only).
// K staged with slot ^= (row&7) pre-swizzled source; V^T with slot ^= (d&15); ds_read
// applies the same XOR -> low-conflict.
// Per-wave math (verified R3-R8): S^T = mfma(K,Q) 32x32x16 (C/D: col=lane&31,
// row=(r&3)+8*(r>>2)+4*(lane>>5)); in-register softmax at q=l31 with TREE max/sum
// (depth 6 vs 63-op serial chain); P^T via cvt_pk + v_permlane32_swap_b32;
// O^T += mfma(V^T, P^T); deferred-rescale THR=8 (log2 units).
__global__ __launch_bounds__(256) void attn_fwd_kernel(
    const unsigned short* __restrict__ Q,
    const unsigned short* __restrict__ K,
    const unsigned short* __restrict__ Vt,
    unsigned short* __restrict__ O)
{
    const int idx = blockIdx.x;
    const int qt = (idx < 256) ? (15 - (idx >> 5)) : ((idx - 256) >> 5);
    const int bh = idx & 31;
    const int w = threadIdx.x >> 6;
    const int lane = threadIdx.x & 63;
    const int l31 = lane & 31, hi = lane >> 5;
    const int qw = qt * 128 + 32 * w;

    const unsigned short* Qh = Q + (size_t)bh * T_SZ * D_SZ;
    const unsigned short* Kh = K + (size_t)bh * T_SZ * D_SZ;
    const unsigned short* Vh = Vt + (size_t)bh * T_SZ * D_SZ;   // (D,T) layout

    // double buffer: buf b at smem + b*16384: K tile [0,8192) (128r x 64), V^T tile
    // [8192,16384) (64r x 128) ushorts.
    __shared__ __align__(16) unsigned short smem[32768];

    // K staging: 1024 chunks of 16B; thread covers c0 + 256*ii (ii=0..3).
    // chunk c: row=c>>3 (0..127), slot=c&7, swz slot^(row&7); +256 chunks = +32 rows keeps
    // row&7 invariant. LDS dest (linear chunk order) = base + w*512 + ii*2048.
    const int c0 = w * 64 + lane;
    const int krow0 = c0 >> 3;
    const int ksw0 = (c0 & 7) ^ (krow0 & 7);
    const int koff0 = krow0 * 64 + ksw0 * 8;        // ushort offset in K source
    // V staging: 1024 chunks; chunk c: d=c>>4 (0..63), slot=c&15, swz slot^(d&15);
    // +256 chunks = +16 d-rows keeps d&15 invariant.
    const int vrow0 = c0 >> 4;
    const int vsw0 = (c0 & 15) ^ (vrow0 & 15);
    const int voff0 = vrow0 * T_SZ + vsw0 * 8;      // ushort offset in V^T source
    const int ldsb0 = w * 512;                      // wave-uniform LDS dest base

    // Q B-frags: q = qw + l31, k-chunks j*16 + 8*hi
    bf16x8 qf[4];
    #pragma unroll
    for (int j = 0; j < 4; j++)
        qf[j] = *(const bf16x8*)&Qh[(size_t)(qw + l31) * D_SZ + j * 16 + 8 * hi];

    f32x16 acc[2];                 // O^T: d-tiles 0/1, q=l31 cols
    #pragma unroll
    for (int r = 0; r < 16; r++) { acc[0][r] = 0.f; acc[1][r] = 0.f; }
    float mrun = -3.0e38f, lrun = 0.f;

    const int ntb = qt + 1;        // all waves compute every tile
    const int qrow = qw + l31;
    const int kswl = l31 & 7;
    const int vswl = l31 & 15;

    // ---- prologue: stage tile 0 into buffer 0 (8 loads in flight) ----
    #pragma unroll
    for (int ii = 0; ii < 4; ii++)
        load_lds16(Kh + koff0 + ii * 2048, smem + ldsb0 + ii * 2048);
    #pragma unroll
    for (int ii = 0; ii < 4; ii++)
        load_lds16(Vh + voff0 + ii * 16 * T_SZ, smem + 8192 + ldsb0 + ii * 2048);

    for (int tt = 0; tt < ntb; ++tt) {
        // ---- issue next tile's staging, then wait only for tile tt's loads ----
        if (tt + 1 < ntb) {
            unsigned short* Bd = smem + ((tt + 1) & 1) * 16384;
            const unsigned short* Kt = Kh + (size_t)(tt + 1) * 128 * D_SZ;
            const unsigned short* Vtt = Vh + (tt + 1) * 128;
            #pragma unroll
            for (int ii = 0; ii < 4; ii++)
                load_lds16(Kt + koff0 + ii * 2048, Bd + ldsb0 + ii * 2048);
            #pragma unroll
            for (int ii = 0; ii < 4; ii++)
                load_lds16(Vtt + voff0 + ii * 16 * T_SZ, Bd + 8192 + ldsb0 + ii * 2048);
            asm volatile("s_waitcnt vmcnt(8)" ::: "memory");
        } else {
            asm volatile("s_waitcnt vmcnt(0)" ::: "memory");
        }
        __builtin_amdgcn_s_barrier();   // tile tt visible to all waves

        {
            const unsigned short* Ks = smem + (tt & 1) * 16384;
            const unsigned short* Vs = Ks + 8192;
            const int k0 = tt * 128;

            // S^T = K Q^T (128kv x 32q) over D=64, four 32-kv blocks
            f32x16 s[4];
            #pragma unroll
            for (int kb = 0; kb < 4; ++kb) {
                bf16x8 kf[4];
                #pragma unroll
                for (int j = 0; j < 4; ++j) {
                    const int ch = (j * 2 + hi) ^ kswl;
                    kf[j] = *(const bf16x8*)&Ks[(kb * 32 + l31) * 64 + ch * 8];
                }
                f32x16 sc;
                #pragma unroll
                for (int r = 0; r < 16; r++) sc[r] = 0.f;
                #pragma unroll
                for (int j = 0; j < 4; ++j)
                    sc = __builtin_amdgcn_mfma_f32_32x32x16_bf16(kf[j], qf[j], sc, 0, 0, 0);
                s[kb] = sc;
            }

            // causal mask (only the diagonal tile tt == qt)
            if (tt == ntb - 1) {
                #pragma unroll
                for (int kb = 0; kb < 4; ++kb)
                    #pragma unroll
                    for (int r = 0; r < 16; ++r) {
                        const int kv = k0 + kb * 32 + (r & 3) + 8 * (r >> 2) + 4 * hi;
                        s[kb][r] = (kv > qrow) ? -3.0e38f : s[kb][r];
                    }
            }

            // in-register row max over 64 values (tree, depth 6)
            float t32[32];
            #pragma unroll
            for (int i = 0; i < 32; i++)
                t32[i] = fmaxf(s[(2 * i) >> 4][(2 * i) & 15], s[(2 * i + 1) >> 4][(2 * i + 1) & 15]);
            #pragma unroll
            for (int st = 16; st >= 1; st >>= 1)
                #pragma unroll
                for (int i = 0; i < st; i++)
                    t32[i] = fmaxf(t32[i], t32[i + st]);
            const float pm = fmaxf(t32[0], __shfl_xor(t32[0], 32));

            // deferred-rescale (T13, THR=8 in log2 units)
            if (!__all(pm <= mrun + 8.0f)) {
                const float mnew = fmaxf(mrun, pm);
                const float al = exp2f(mrun - mnew);
                lrun *= al;
                #pragma unroll
                for (int r = 0; r < 16; r++) { acc[0][r] *= al; acc[1][r] *= al; }
                mrun = mnew;
            }

            // P = exp2(s - m); row sum (tree)
            #pragma unroll
            for (int kb = 0; kb < 4; ++kb)
                #pragma unroll
                for (int r = 0; r < 16; r++) s[kb][r] = exp2f(s[kb][r] - mrun);
            float a32[32];
            #pragma unroll
            for (int i = 0; i < 32; i++)
                a32[i] = s[(2 * i) >> 4][(2 * i) & 15] + s[(2 * i + 1) >> 4][(2 * i + 1) & 15];
            #pragma unroll
            for (int st = 16; st >= 1; st >>= 1)
                #pragma unroll
                for (int i = 0; i < st; i++)
                    a32[i] += a32[i + st];
            lrun += a32[0] + __shfl_xor(a32[0], 32);

            // pack P -> P^T B-frags via cvt_pk + permlane32_swap (per 16-kv k-step)
            bf16x8 pf[4][2];
            #pragma unroll
            for (int kb = 0; kb < 4; ++kb) {
                #pragma unroll
                for (int ksl = 0; ksl < 2; ++ksl) {
                    unsigned a0 = pkbf(s[kb][8 * ksl + 0], s[kb][8 * ksl + 1]);
                    unsigned a1 = pkbf(s[kb][8 * ksl + 2], s[kb][8 * ksl + 3]);
                    unsigned b0 = pkbf(s[kb][8 * ksl + 4], s[kb][8 * ksl + 5]);
                    unsigned b1 = pkbf(s[kb][8 * ksl + 6], s[kb][8 * ksl + 7]);
                    asm volatile("v_permlane32_swap_b32 %0, %1" : "+v"(a0), "+v"(b0));
                    asm volatile("v_permlane32_swap_b32 %0, %1" : "+v"(a1), "+v"(b1));
                    union { unsigned u[4]; bf16x8 v; } fr;
                    fr.u[0] = a0; fr.u[1] = a1; fr.u[2] = b0; fr.u[3] = b1;
                    pf[kb][ksl] = fr.v;
                }
            }

            // O^T += V^T P^T (V^T frags from swizzled LDS; V tile rows are 128 ushorts)
            #pragma unroll
            for (int dt = 0; dt < 2; ++dt)
                #pragma unroll
                for (int kb = 0; kb < 4; ++kb)
                    #pragma unroll
                    for (int ksl = 0; ksl < 2; ++ksl) {
                        const int ks = kb * 2 + ksl;
                        const int ch = (ks * 2 + hi) ^ vswl;
                        const bf16x8 vf = *(const bf16x8*)&Vs[(dt * 32 + l31) * 128 + ch * 8];
                        acc[dt] = __builtin_amdgcn_mfma_f32_32x32x16_bf16(vf, pf[kb][ksl], acc[dt], 0, 0, 0);
                    }
        }
        __builtin_amdgcn_s_barrier();   // all waves done reading buf[tt&1] before its re-stage
    }

    // ---- epilogue: normalize, per-wave LDS transpose O^T -> O rows, coalesced store ----
    unsigned short* ot = smem + w * 2304;   // 32 q rows x stride 72 (per-wave private)
    const float inv = 1.0f / lrun;
    #pragma unroll
    for (int g = 0; g < 4; g++) {
        ushort4 wa, wb;
        wa.x = f2bf(acc[0][4 * g + 0] * inv); wa.y = f2bf(acc[0][4 * g + 1] * inv);
        wa.z = f2bf(acc[0][4 * g + 2] * inv); wa.w = f2bf(acc[0][4 * g + 3] * inv);
        wb.x = f2bf(acc[1][4 * g + 0] * inv); wb.y = f2bf(acc[1][4 * g + 1] * inv);
        wb.z = f2bf(acc[1][4 * g + 2] * inv); wb.w = f2bf(acc[1][4 * g + 3] * inv);
        *(ushort4*)&ot[l31 * 72 + 8 * g + 4 * hi] = wa;        // d-tile 0: d = 8g+4hi+e
        *(ushort4*)&ot[l31 * 72 + 32 + 8 * g + 4 * hi] = wb;   // d-tile 1
    }
    const int b = bh >> 4, h = bh & 15;
    #pragma unroll
    for (int pss = 0; pss < 4; pss++) {
        const int q = pss * 8 + (lane >> 3);
        const uint4 val = *(const uint4*)&ot[q * 72 + (lane & 7) * 8];
        *(uint4*)&O[((size_t)(b * T_SZ + qw + q)) * C_SZ + h * D_SZ + (lane & 7) * 8] = val;
    }
}

// ---------------- launch ----------------

extern "C" void kernel_launch(void* const* d_in, const int* in_sizes, int n_in,
                              void* d_out, int out_size, void* d_ws, size_t ws_size,
                              hipStream_t stream)
{
    const float* x  = (const float*)d_in[0];
    const float* Wq = (const float*)d_in[1];
    const float* bq = (const float*)d_in[2];
    const float* Wk = (const float*)d_in[3];
    const float* bk = (const float*)d_in[4];
    const float* Wv = (const float*)d_in[5];
    const float* bv = (const float*)d_in[6];
    const float* Wo = (const float*)d_in[7];
    const float* bo = (const float*)d_in[8];

    uint8_t* ws = (uint8_t*)d_ws;
    unsigned short* XB   = (unsigned short*)(ws);                        // 8 MB
    unsigned short* WT   = (unsigned short*)(ws + (8u  << 20));          // 8 MB (q,k,v,o)
    unsigned short* QKV  = (unsigned short*)(ws + (16u << 20));          // Q, K, V^T (24 MB)
    unsigned short* Vtmp = (unsigned short*)(ws + (40u << 20));          // V staging, then attn O

    cvt_x_kernel<<<2048, 256, 0, stream>>>((const float4*)x, (ushort4*)XB, M_SZ * C_SZ / 4);
    transpose_cvt_kernel<<<dim3(32, 32, 4), dim3(32, 8), 0, stream>>>(
        Wq, Wk, Wv, Wo, WT, WT + CC, WT + 2 * (size_t)CC, WT + 3 * (size_t)CC);
    gemm_qkv_kernel<<<dim3(8, 32, 3), 256, 0, stream>>>(XB, WT, bq, bk, bv, QKV, Vtmp);
    vt_kernel<<<dim3(64, 2, 32), dim3(32, 8), 0, stream>>>(Vtmp, QKV + 2 * (size_t)BHTD);
    attn_fwd_kernel<<<512, 256, 0, stream>>>(
        QKV, QKV + BHTD, QKV + 2 * (size_t)BHTD, Vtmp);
    gemm_out_kernel<<<dim3(8, 32), 256, 0, stream>>>(Vtmp, WT + 3 * (size_t)CC, bo, (float*)d_out);
}

// Round 10
// 129.019 us; speedup vs baseline: 1.1266x; 1.1266x over previous
//
#include <hip/hip_runtime.h>
#include <stdint.h>
#include <stddef.h>

// Causal attention fused layer for MI355X (gfx950).
// B=2 T=2048 C=1024 H=16 D=64.
// Pipeline: cvt x -> bf16 | transpose-cvt weights -> bf16 N*K | fused QKV GEMM (1 dispatch)
//           | V transpose (B,H,D,T) | flash attention (R8 structure: swapped QK^T, 4-wave
//             blocks, dbuf 64-kv LDS tiles, counted-vmcnt, XOR-swizzle, tree softmax)
//           | out GEMM f32 (64x128 tiles, 512 blocks).
// Workspace layout (needs >= 48 MB):
//   [0,8MB)   x bf16            (M=4096 x K=1024)
//   [8,16MB)  Wt q,k,v,o bf16   (4 x 1024x1024, transposed N x K)
//   [16,32MB) Q,K bf16          ((B,H,T,D)), Q pre-scaled by 0.125*log2(e)
//   [32,40MB) V^T bf16          ((B,H,D,T))
//   [40,48MB) Vtmp then O bf16  (V normal layout, overwritten by attn output (B,T,C))

#define B_SZ 2
#define T_SZ 2048
#define C_SZ 1024
#define H_SZ 16
#define D_SZ 64
#define M_SZ (B_SZ * T_SZ)              // 4096
#define BHTD (B_SZ * H_SZ * T_SZ * D_SZ) // 4194304
#define CC (C_SZ * C_SZ)                 // 1048576

typedef __attribute__((ext_vector_type(8))) __bf16 bf16x8;
typedef __attribute__((ext_vector_type(4))) float f32x4;
typedef __attribute__((ext_vector_type(16))) float f32x16;

__device__ __forceinline__ unsigned short f2bf(float f) {
    union { float f; unsigned u; } v; v.f = f;
    v.u += 0x7fffu + ((v.u >> 16) & 1u);   // round-to-nearest-even
    return (unsigned short)(v.u >> 16);
}

__device__ __forceinline__ unsigned pkbf(float lo, float hi_) {
    union { unsigned u; __bf16 h[2]; } r;
    r.h[0] = (__bf16)lo; r.h[1] = (__bf16)hi_;    // compiler emits v_cvt_pk_bf16_f32
    return r.u;
}

__device__ __forceinline__ void load_lds16(const unsigned short* g, unsigned short* l) {
    __builtin_amdgcn_global_load_lds(
        (const __attribute__((address_space(1))) void*)g,
        (__attribute__((address_space(3))) void*)l, 16, 0, 0);
}

// ---------------- conversion kernels ----------------

__global__ void cvt_x_kernel(const float4* __restrict__ in, ushort4* __restrict__ out, int n4) {
    int stride = gridDim.x * blockDim.x;
    for (int i = blockIdx.x * blockDim.x + threadIdx.x; i < n4; i += stride) {
        float4 v = in[i];
        ushort4 o;
        o.x = f2bf(v.x); o.y = f2bf(v.y); o.z = f2bf(v.z); o.w = f2bf(v.w);
        out[i] = o;
    }
}

__global__ __launch_bounds__(256) void transpose_cvt_kernel(
    const float* __restrict__ W0, const float* __restrict__ W1,
    const float* __restrict__ W2, const float* __restrict__ W3,
    unsigned short* __restrict__ T0, unsigned short* __restrict__ T1,
    unsigned short* __restrict__ T2, unsigned short* __restrict__ T3)
{
    __shared__ float tile[32][33];
    const float* W; unsigned short* Wt;
    switch (blockIdx.z) {
        case 0: W = W0; Wt = T0; break;
        case 1: W = W1; Wt = T1; break;
        case 2: W = W2; Wt = T2; break;
        default: W = W3; Wt = T3; break;
    }
    const int tx = threadIdx.x, ty = threadIdx.y;     // 32 x 8
    const int n0 = blockIdx.x * 32, k0 = blockIdx.y * 32;
    #pragma unroll
    for (int i = 0; i < 4; i++)
        tile[ty + i * 8][tx] = W[(size_t)(k0 + ty + i * 8) * C_SZ + n0 + tx];
    __syncthreads();
    #pragma unroll
    for (int i = 0; i < 4; i++)
        Wt[(size_t)(n0 + ty + i * 8) * C_SZ + k0 + tx] = f2bf(tile[tx][ty + i * 8]);
}

// V (B,H,T,D) -> V^T (B,H,D,T), per-head 2048x64 transpose in 32x32 tiles.
__global__ __launch_bounds__(256) void vt_kernel(
    const unsigned short* __restrict__ V, unsigned short* __restrict__ Vt)
{
    __shared__ unsigned short tile[32][33];
    const int bh = blockIdx.z;
    const int t0 = blockIdx.x * 32, d0 = blockIdx.y * 32;
    const unsigned short* src = V + (size_t)bh * T_SZ * D_SZ;
    unsigned short* dst = Vt + (size_t)bh * T_SZ * D_SZ;
    const int tx = threadIdx.x, ty = threadIdx.y;     // 32 x 8
    #pragma unroll
    for (int i = 0; i < 4; i++)
        tile[ty + i * 8][tx] = src[(size_t)(t0 + ty + i * 8) * D_SZ + d0 + tx];
    __syncthreads();
    #pragma unroll
    for (int i = 0; i < 4; i++)
        dst[(size_t)(d0 + ty + i * 8) * T_SZ + t0 + tx] = tile[tx][ty + i * 8];
}

// ---------------- GEMM core (m97 structure: 128x128 tile, BK=32) ----------------

__device__ __forceinline__ void gemm_tile_core(
    const unsigned short* __restrict__ A,
    const unsigned short* __restrict__ Bt,
    unsigned short* As, unsigned short* Bs,
    int m0, int n0, f32x4 acc[4][4])
{
    const int tid = threadIdx.x;
    const int lane = tid & 63;
    const int w = tid >> 6;
    const int l15 = lane & 15, lg = lane >> 4;
    const int wr = (w >> 1) * 64, wc = (w & 1) * 64;

    const unsigned short* Ag0 = A + (size_t)(m0 + (tid >> 2)) * C_SZ + (tid & 3) * 8;
    const unsigned short* Ag1 = Ag0 + (size_t)64 * C_SZ;
    const unsigned short* Bg0 = Bt + (size_t)(n0 + (tid >> 2)) * C_SZ + (tid & 3) * 8;
    const unsigned short* Bg1 = Bg0 + (size_t)64 * C_SZ;
    unsigned short* As0 = As + w * 512;
    unsigned short* As1 = As + 2048 + w * 512;
    unsigned short* Bs0 = Bs + w * 512;
    unsigned short* Bs1 = Bs + 2048 + w * 512;

    for (int k0 = 0; k0 < C_SZ; k0 += 32) {
        load_lds16(Ag0 + k0, As0);
        load_lds16(Ag1 + k0, As1);
        load_lds16(Bg0 + k0, Bs0);
        load_lds16(Bg1 + k0, Bs1);
        __syncthreads();
        bf16x8 af[4], bfv[4];
        const bf16x8* Ap = (const bf16x8*)As;
        const bf16x8* Bp = (const bf16x8*)Bs;
        #pragma unroll
        for (int m = 0; m < 4; m++) af[m] = Ap[(wr + m * 16 + l15) * 4 + lg];
        #pragma unroll
        for (int n = 0; n < 4; n++) bfv[n] = Bp[(wc + n * 16 + l15) * 4 + lg];
        #pragma unroll
        for (int m = 0; m < 4; m++)
            #pragma unroll
            for (int n = 0; n < 4; n++)
                acc[m][n] = __builtin_amdgcn_mfma_f32_16x16x32_bf16(af[m], bfv[n], acc[m][n], 0, 0, 0);
        __syncthreads();
    }
}

// Fused QKV projection GEMM: ONE dispatch, grid (24, 32); z = blockIdx.x>>3 selects Q/K/V,
// n0 = (blockIdx.x&7)*128. Q,K -> (B,H,T,D) bf16 (Q scaled by 0.125*log2(e)); V -> Vtmp.
__global__ __launch_bounds__(256) void gemm_qkv_kernel(
    const unsigned short* __restrict__ A,
    const unsigned short* __restrict__ WtBase,
    const float* __restrict__ bq, const float* __restrict__ bk, const float* __restrict__ bv,
    unsigned short* __restrict__ QKV, unsigned short* __restrict__ Vtmp)
{
    __shared__ unsigned short As[4096], Bs[4096];
    const int z = blockIdx.x >> 3;
    const unsigned short* Bt = WtBase + (size_t)z * CC;
    const float* bias = (z == 0) ? bq : (z == 1) ? bk : bv;
    const float scale = (z == 0) ? 0.18033688011112042f : 1.0f;  // 0.125 * log2(e)
    unsigned short* Out = (z == 2) ? Vtmp : QKV + (size_t)z * BHTD;

    f32x4 acc[4][4];
    f32x4 zero4 = {0.f, 0.f, 0.f, 0.f};
    #pragma unroll
    for (int m = 0; m < 4; m++)
        #pragma unroll
        for (int n = 0; n < 4; n++) acc[m][n] = zero4;

    const int m0 = blockIdx.y * 128, n0 = (blockIdx.x & 7) * 128;
    gemm_tile_core(A, Bt, As, Bs, m0, n0, acc);

    const int lane = threadIdx.x & 63;
    const int w = threadIdx.x >> 6;
    const int l15 = lane & 15, lg = lane >> 4;
    const int wr = (w >> 1) * 64, wc = (w & 1) * 64;
    #pragma unroll
    for (int n = 0; n < 4; n++) {
        const int col = n0 + wc + n * 16 + l15;
        const float bias_v = bias[col];
        const int h = col >> 6, d = col & 63;
        #pragma unroll
        for (int m = 0; m < 4; m++) {
            #pragma unroll
            for (int j = 0; j < 4; j++) {
                const int row = m0 + wr + m * 16 + lg * 4 + j;   // global M row = b*T + t
                const int b = row >> 11, t = row & (T_SZ - 1);
                Out[(((size_t)(b * H_SZ + h)) * T_SZ + t) * D_SZ + d] =
                    f2bf((acc[m][n][j] + bias_v) * scale);
            }
        }
    }
}

// Output projection GEMM: 64x128 tiles (grid 8 x 64 = 512 blocks -> 2 blocks/CU).
// 4 waves, wave w computes rows 0..63 x cols [w*32, w*32+32): acc[4][2].
// Per K-step: 3 global_load_lds/thread, 6 ds_read_b128, 8 MFMA per wave.
__global__ __launch_bounds__(256) void gemm_out_kernel(
    const unsigned short* __restrict__ A,
    const unsigned short* __restrict__ Bt,
    const float* __restrict__ bo,
    float* __restrict__ Out)
{
    __shared__ unsigned short As[2048], Bs[4096];
    const int tid = threadIdx.x;
    const int lane = tid & 63;
    const int w = tid >> 6;
    const int l15 = lane & 15, lg = lane >> 4;
    const int wc = w * 32;
    const int m0 = blockIdx.y * 64, n0 = blockIdx.x * 128;

    // A-tile: 64 rows x 32k = 256 chunks of 16B, thread -> chunk tid.
    // B-tile: 128 rows x 32k = 512 chunks, thread -> chunks tid, tid+256.
    const unsigned short* Ag  = A + (size_t)(m0 + (tid >> 2)) * C_SZ + (tid & 3) * 8;
    const unsigned short* Bg0 = Bt + (size_t)(n0 + (tid >> 2)) * C_SZ + (tid & 3) * 8;
    const unsigned short* Bg1 = Bg0 + (size_t)64 * C_SZ;
    unsigned short* As0 = As + w * 512;
    unsigned short* Bs0 = Bs + w * 512;
    unsigned short* Bs1 = Bs + 2048 + w * 512;

    f32x4 acc[4][2];
    f32x4 zero4 = {0.f, 0.f, 0.f, 0.f};
    #pragma unroll
    for (int m = 0; m < 4; m++)
        #pragma unroll
        for (int n = 0; n < 2; n++) acc[m][n] = zero4;

    for (int k0 = 0; k0 < C_SZ; k0 += 32) {
        load_lds16(Ag + k0, As0);
        load_lds16(Bg0 + k0, Bs0);
        load_lds16(Bg1 + k0, Bs1);
        __syncthreads();
        bf16x8 af[4], bfv[2];
        const bf16x8* Ap = (const bf16x8*)As;
        const bf16x8* Bp = (const bf16x8*)Bs;
        #pragma unroll
        for (int m = 0; m < 4; m++) af[m] = Ap[(m * 16 + l15) * 4 + lg];
        #pragma unroll
        for (int n = 0; n < 2; n++) bfv[n] = Bp[(wc + n * 16 + l15) * 4 + lg];
        #pragma unroll
        for (int m = 0; m < 4; m++)
            #pragma unroll
            for (int n = 0; n < 2; n++)
                acc[m][n] = __builtin_amdgcn_mfma_f32_16x16x32_bf16(af[m], bfv[n], acc[m][n], 0, 0, 0);
        __syncthreads();
    }

    #pragma unroll
    for (int n = 0; n < 2; n++) {
        const int col = n0 + wc + n * 16 + l15;
        const float bias_v = bo[col];
        #pragma unroll
        for (int m = 0; m < 4; m++) {
            #pragma unroll
            for (int j = 0; j < 4; j++) {
                const int row = m0 + m * 16 + lg * 4 + j;
                Out[(size_t)row * C_SZ + col] = acc[m][n][j] + bias_v;
            }
        }
    }
}

// ---------------- flash attention (R8 structure + tree softmax reductions) ----------------
// grid 512 x 256thr (4 waves). qt pairing decode, bh = idx&31. Block owns 128 q rows
// (wave w: qw = qt*128 + 32w); all waves share staged 64-kv tiles (dbuf 2x16KB = 32KB).
// Pipeline (T3+T4): issue STAGE(t+1) -> s_waitcnt vmcnt(4) -> s_barrier -> compute(t) ->
// s_barrier. vmcnt never 0 in-loop. K/V^T staged via global_load_lds with pre-swizzled
// source (slot ^= row&7); ds_read applies the same XOR.
// Math (verified R3-R8): S^T = mfma(K,Q) 32x32x16 (C/D: col=lane&31,
// row=(r&3)+8*(r>>2)+4*(lane>>5)); in-register softmax at q=l31 with depth-5 TREE max/sum;
// P^T via cvt_pk + v_permlane32_swap_b32; O^T += mfma(V^T, P^T); deferred-rescale THR=8.
__global__ __launch_bounds__(256) void attn_fwd_kernel(
    const unsigned short* __restrict__ Q,
    const unsigned short* __restrict__ K,
    const unsigned short* __restrict__ Vt,
    unsigned short* __restrict__ O)
{
    const int idx = blockIdx.x;
    const int qt = (idx < 256) ? (15 - (idx >> 5)) : ((idx - 256) >> 5);
    const int bh = idx & 31;
    const int w = threadIdx.x >> 6;
    const int lane = threadIdx.x & 63;
    const int l31 = lane & 31, hi = lane >> 5;
    const int qw = qt * 128 + 32 * w;

    const unsigned short* Qh = Q + (size_t)bh * T_SZ * D_SZ;
    const unsigned short* Kh = K + (size_t)bh * T_SZ * D_SZ;
    const unsigned short* Vh = Vt + (size_t)bh * T_SZ * D_SZ;   // (D,T) layout

    __shared__ __align__(16) unsigned short smem[16384];

    const int c0 = w * 64 + lane;
    const int row0 = c0 >> 3;
    const int sw0 = (c0 & 7) ^ (row0 & 7);
    const int koff0 = row0 * 64 + sw0 * 8;
    const int voff0 = row0 * T_SZ + sw0 * 8;
    const int ldsb0 = w * 512;

    bf16x8 qf[4];
    #pragma unroll
    for (int j = 0; j < 4; j++)
        qf[j] = *(const bf16x8*)&Qh[(size_t)(qw + l31) * D_SZ + j * 16 + 8 * hi];

    f32x16 acc[2];
    #pragma unroll
    for (int r = 0; r < 16; r++) { acc[0][r] = 0.f; acc[1][r] = 0.f; }
    float mrun = -3.0e38f, lrun = 0.f;

    const int tlast = (qw + 31) >> 6;
    const int ntb = 2 * qt + 2;
    const int qrow = qw + l31;
    const int swl = l31 & 7;

    // ---- prologue: stage tile 0 into buffer 0 (4 loads in flight) ----
    load_lds16(Kh + koff0, smem + ldsb0);
    load_lds16(Kh + koff0 + 2048, smem + 2048 + ldsb0);
    load_lds16(Vh + voff0, smem + 4096 + ldsb0);
    load_lds16(Vh + voff0 + 32 * T_SZ, smem + 6144 + ldsb0);

    for (int tt = 0; tt < ntb; ++tt) {
        if (tt + 1 < ntb) {
            unsigned short* Bd = smem + ((tt + 1) & 1) * 8192;
            const unsigned short* Kt = Kh + (size_t)(tt + 1) * 64 * D_SZ;
            const unsigned short* Vtt = Vh + (tt + 1) * 64;
            load_lds16(Kt + koff0, Bd + ldsb0);
            load_lds16(Kt + koff0 + 2048, Bd + 2048 + ldsb0);
            load_lds16(Vtt + voff0, Bd + 4096 + ldsb0);
            load_lds16(Vtt + voff0 + 32 * T_SZ, Bd + 6144 + ldsb0);
            asm volatile("s_waitcnt vmcnt(4)" ::: "memory");
        } else {
            asm volatile("s_waitcnt vmcnt(0)" ::: "memory");
        }
        __builtin_amdgcn_s_barrier();

        if (tt <= tlast) {
            const unsigned short* Ks = smem + (tt & 1) * 8192;
            const unsigned short* Vs = Ks + 4096;
            const int k0 = tt * 64;

            // S^T = K Q^T (64kv x 32q) over D=64
            f32x16 s[2];
            #pragma unroll
            for (int kb = 0; kb < 2; ++kb) {
                bf16x8 kf[4];
                #pragma unroll
                for (int j = 0; j < 4; ++j) {
                    const int ch = (j * 2 + hi) ^ swl;
                    kf[j] = *(const bf16x8*)&Ks[(kb * 32 + l31) * 64 + ch * 8];
                }
                f32x16 sc;
                #pragma unroll
                for (int r = 0; r < 16; r++) sc[r] = 0.f;
                #pragma unroll
                for (int j = 0; j < 4; ++j)
                    sc = __builtin_amdgcn_mfma_f32_32x32x16_bf16(kf[j], qf[j], sc, 0, 0, 0);
                s[kb] = sc;
            }

            // causal mask (tiles overlapping this wave's diagonal)
            if (k0 + 63 > qw) {
                #pragma unroll
                for (int kb = 0; kb < 2; ++kb)
                    #pragma unroll
                    for (int r = 0; r < 16; ++r) {
                        const int kv = k0 + kb * 32 + (r & 3) + 8 * (r >> 2) + 4 * hi;
                        s[kb][r] = (kv > qrow) ? -3.0e38f : s[kb][r];
                    }
            }

            // row max over 32 lane-local values (tree, depth 5) + cross-half
            float t16[16];
            #pragma unroll
            for (int i = 0; i < 16; i++) t16[i] = fmaxf(s[0][i], s[1][i]);
            #pragma unroll
            for (int st = 8; st >= 1; st >>= 1)
                #pragma unroll
                for (int i = 0; i < st; i++) t16[i] = fmaxf(t16[i], t16[i + st]);
            const float pm = fmaxf(t16[0], __shfl_xor(t16[0], 32));

            // deferred-rescale (T13, THR=8 in log2 units)
            if (!__all(pm <= mrun + 8.0f)) {
                const float mnew = fmaxf(mrun, pm);
                const float al = exp2f(mrun - mnew);
                lrun *= al;
                #pragma unroll
                for (int r = 0; r < 16; r++) { acc[0][r] *= al; acc[1][r] *= al; }
                mrun = mnew;
            }

            // P = exp2(s - m); row sum (tree)
            #pragma unroll
            for (int kb = 0; kb < 2; ++kb)
                #pragma unroll
                for (int r = 0; r < 16; r++) s[kb][r] = exp2f(s[kb][r] - mrun);
            float a16[16];
            #pragma unroll
            for (int i = 0; i < 16; i++) a16[i] = s[0][i] + s[1][i];
            #pragma unroll
            for (int st = 8; st >= 1; st >>= 1)
                #pragma unroll
                for (int i = 0; i < st; i++) a16[i] += a16[i + st];
            lrun += a16[0] + __shfl_xor(a16[0], 32);

            // pack P -> P^T B-frags via cvt_pk + permlane32_swap
            bf16x8 pf[2][2];
            #pragma unroll
            for (int kb = 0; kb < 2; ++kb) {
                #pragma unroll
                for (int ksl = 0; ksl < 2; ++ksl) {
                    unsigned a0 = pkbf(s[kb][8 * ksl + 0], s[kb][8 * ksl + 1]);
                    unsigned a1 = pkbf(s[kb][8 * ksl + 2], s[kb][8 * ksl + 3]);
                    unsigned b0 = pkbf(s[kb][8 * ksl + 4], s[kb][8 * ksl + 5]);
                    unsigned b1 = pkbf(s[kb][8 * ksl + 6], s[kb][8 * ksl + 7]);
                    asm volatile("v_permlane32_swap_b32 %0, %1" : "+v"(a0), "+v"(b0));
                    asm volatile("v_permlane32_swap_b32 %0, %1" : "+v"(a1), "+v"(b1));
                    union { unsigned u[4]; bf16x8 v; } fr;
                    fr.u[0] = a0; fr.u[1] = a1; fr.u[2] = b0; fr.u[3] = b1;
                    pf[kb][ksl] = fr.v;
                }
            }

            // O^T += V^T P^T
            #pragma unroll
            for (int dt = 0; dt < 2; ++dt)
                #pragma unroll
                for (int kb = 0; kb < 2; ++kb)
                    #pragma unroll
                    for (int ksl = 0; ksl < 2; ++ksl) {
                        const int ks = kb * 2 + ksl;
                        const int ch = (ks * 2 + hi) ^ swl;
                        const bf16x8 vf = *(const bf16x8*)&Vs[(dt * 32 + l31) * 64 + ch * 8];
                        acc[dt] = __builtin_amdgcn_mfma_f32_32x32x16_bf16(vf, pf[kb][ksl], acc[dt], 0, 0, 0);
                    }
        }
        __builtin_amdgcn_s_barrier();
    }

    // ---- epilogue: normalize, per-wave LDS transpose O^T -> O rows, coalesced store ----
    unsigned short* ot = smem + w * 2304;   // 32 q rows x stride 72 (per-wave private)
    const float inv = 1.0f / lrun;
    #pragma unroll
    for (int g = 0; g < 4; g++) {
        ushort4 wa, wb;
        wa.x = f2bf(acc[0][4 * g + 0] * inv); wa.y = f2bf(acc[0][4 * g + 1] * inv);
        wa.z = f2bf(acc[0][4 * g + 2] * inv); wa.w = f2bf(acc[0][4 * g + 3] * inv);
        wb.x = f2bf(acc[1][4 * g + 0] * inv); wb.y = f2bf(acc[1][4 * g + 1] * inv);
        wb.z = f2bf(acc[1][4 * g + 2] * inv); wb.w = f2bf(acc[1][4 * g + 3] * inv);
        *(ushort4*)&ot[l31 * 72 + 8 * g + 4 * hi] = wa;        // d-tile 0: d = 8g+4hi+e
        *(ushort4*)&ot[l31 * 72 + 32 + 8 * g + 4 * hi] = wb;   // d-tile 1
    }
    const int b = bh >> 4, h = bh & 15;
    #pragma unroll
    for (int pss = 0; pss < 4; pss++) {
        const int q = pss * 8 + (lane >> 3);
        const uint4 val = *(const uint4*)&ot[q * 72 + (lane & 7) * 8];
        *(uint4*)&O[((size_t)(b * T_SZ + qw + q)) * C_SZ + h * D_SZ + (lane & 7) * 8] = val;
    }
}

// ---------------- launch ----------------

extern "C" void kernel_launch(void* const* d_in, const int* in_sizes, int n_in,
                              void* d_out, int out_size, void* d_ws, size_t ws_size,
                              hipStream_t stream)
{
    const float* x  = (const float*)d_in[0];
    const float* Wq = (const float*)d_in[1];
    const float* bq = (const float*)d_in[2];
    const float* Wk = (const float*)d_in[3];
    const float* bk = (const float*)d_in[4];
    const float* Wv = (const float*)d_in[5];
    const float* bv = (const float*)d_in[6];
    const float* Wo = (const float*)d_in[7];
    const float* bo = (const float*)d_in[8];

    uint8_t* ws = (uint8_t*)d_ws;
    unsigned short* XB   = (unsigned short*)(ws);                        // 8 MB
    unsigned short* WT   = (unsigned short*)(ws + (8u  << 20));          // 8 MB (q,k,v,o)
    unsigned short* QKV  = (unsigned short*)(ws + (16u << 20));          // Q, K, V^T (24 MB)
    unsigned short* Vtmp = (unsigned short*)(ws + (40u << 20));          // V staging, then attn O

    cvt_x_kernel<<<2048, 256, 0, stream>>>((const float4*)x, (ushort4*)XB, M_SZ * C_SZ / 4);
    transpose_cvt_kernel<<<dim3(32, 32, 4), dim3(32, 8), 0, stream>>>(
        Wq, Wk, Wv, Wo, WT, WT + CC, WT + 2 * (size_t)CC, WT + 3 * (size_t)CC);
    gemm_qkv_kernel<<<dim3(24, 32), 256, 0, stream>>>(XB, WT, bq, bk, bv, QKV, Vtmp);
    vt_kernel<<<dim3(64, 2, 32), dim3(32, 8), 0, stream>>>(Vtmp, QKV + 2 * (size_t)BHTD);
    attn_fwd_kernel<<<512, 256, 0, stream>>>(
        QKV, QKV + BHTD, QKV + 2 * (size_t)BHTD, Vtmp);
    gemm_out_kernel<<<dim3(8, 64), 256, 0, stream>>>(Vtmp, WT + 3 * (size_t)CC, bo, (float*)d_out);
}